// Round 14
// baseline (1183.429 us; speedup 1.0000x reference)
//
#include <hip/hip_runtime.h>
#include <stdint.h>

typedef unsigned short ushort_t;
typedef unsigned short us8 __attribute__((ext_vector_type(8)));
typedef __bf16 bf16x8 __attribute__((ext_vector_type(8)));
typedef float f32x4 __attribute__((ext_vector_type(4)));

#define D_MODEL 4096
#define SEQ 1024
#define BROWS 2048
#define QKV_N 6144
#define HD 128
#define FFN_GRID 11008
#define ATTN_MULT 0.08838834764831845f

__device__ __forceinline__ unsigned short f2bf(float f){
  union { float f; unsigned u; } c; c.f = f;
  unsigned u = c.u + 0x7fffu + ((c.u >> 16) & 1u);
  return (unsigned short)(u >> 16);
}
__device__ __forceinline__ float bf2f(unsigned short h){
  union { unsigned u; float f; } c; c.u = ((unsigned)h) << 16;
  return c.f;
}
__device__ __forceinline__ f32x4 zero4(){ f32x4 z; z[0]=0.f; z[1]=0.f; z[2]=0.f; z[3]=0.f; return z; }
__device__ __forceinline__ bf16x8 ldb8(const void* p){ return *(const bf16x8*)p; }
__device__ __forceinline__ f32x4 MFMA(bf16x8 a, bf16x8 b, f32x4 c){
  return __builtin_amdgcn_mfma_f32_16x16x32_bf16(a, b, c, 0, 0, 0);
}
// async global->LDS, 16B per lane; LDS dest = wave-uniform base + lane*16
__device__ __forceinline__ void g2lds16(void* lds, const void* g){
  __builtin_amdgcn_global_load_lds(
      (const __attribute__((address_space(1))) void*)(uintptr_t)(g),
      (__attribute__((address_space(3))) void*)(uint32_t)(uintptr_t)(lds),
      16, 0, 0);
}
#define BAR() __builtin_amdgcn_s_barrier()
#define VMCNT8() asm volatile("s_waitcnt vmcnt(8)" ::: "memory")
#define VMCNT7() asm volatile("s_waitcnt vmcnt(7)" ::: "memory")
#define VMCNT3() asm volatile("s_waitcnt vmcnt(3)" ::: "memory")
#define VMCNT0() asm volatile("s_waitcnt vmcnt(0)" ::: "memory")
#define LGKM0() asm volatile("s_waitcnt lgkmcnt(0)" ::: "memory")

// ---------------- RMSNorm (input) : hn = rms(x)*scale, bf16 out ----------------
__global__ __launch_bounds__(256) void rmsnorm_in(const float* __restrict__ x,
                                                  const float* __restrict__ sc,
                                                  ushort_t* __restrict__ out){
  int row = blockIdx.x, tid = threadIdx.x;
  const float4* xr = (const float4*)(x + (size_t)row*D_MODEL);
  float4 v[4]; float ss = 0.f;
#pragma unroll
  for (int i=0;i<4;i++){
    v[i] = xr[tid + i*256];
    ss += v[i].x*v[i].x + v[i].y*v[i].y + v[i].z*v[i].z + v[i].w*v[i].w;
  }
#pragma unroll
  for (int m=32;m;m>>=1) ss += __shfl_xor(ss, m);
  __shared__ float red[4];
  if ((tid&63)==0) red[tid>>6] = ss;
  __syncthreads();
  float inv = rsqrtf((red[0]+red[1]+red[2]+red[3])*(1.f/4096.f) + 1e-5f);
  const float4* scv = (const float4*)sc;
#pragma unroll
  for (int i=0;i<4;i++){
    float4 s4 = scv[tid + i*256];
    ushort4 o;
    o.x = f2bf(v[i].x*inv*s4.x); o.y = f2bf(v[i].y*inv*s4.y);
    o.z = f2bf(v[i].z*inv*s4.z); o.w = f2bf(v[i].w*inv*s4.w);
    ((ushort4*)out)[(size_t)row*1024 + tid + i*256] = o;
  }
}

// ---- residual+norm: h = base + rms(delta [+ delta2])*sc1 ; opt hn2 = rms(h)*sc2 ----
__global__ __launch_bounds__(256) void rmsnorm_resid(const float* __restrict__ base,
                                                     const float* __restrict__ delta,
                                                     const float* __restrict__ delta2,
                                                     const float* __restrict__ sc1,
                                                     float* __restrict__ hout,
                                                     const float* __restrict__ sc2,
                                                     ushort_t* __restrict__ hn2){
  int row = blockIdx.x, tid = threadIdx.x;
  const float4* dr = (const float4*)(delta + (size_t)row*D_MODEL);
  const float4* d2 = delta2 ? (const float4*)(delta2 + (size_t)row*D_MODEL) : nullptr;
  const float4* br = (const float4*)(base  + (size_t)row*D_MODEL);
  float4 d[4]; float ss = 0.f;
#pragma unroll
  for (int i=0;i<4;i++){
    float4 a = dr[tid + i*256];
    if (d2){
      float4 b = d2[tid + i*256];
      a.x += b.x; a.y += b.y; a.z += b.z; a.w += b.w;
    }
    d[i] = a;
    ss += d[i].x*d[i].x + d[i].y*d[i].y + d[i].z*d[i].z + d[i].w*d[i].w;
  }
#pragma unroll
  for (int m=32;m;m>>=1) ss += __shfl_xor(ss, m);
  __shared__ float red[4];
  if ((tid&63)==0) red[tid>>6] = ss;
  __syncthreads();
  float inv1 = rsqrtf((red[0]+red[1]+red[2]+red[3])*(1.f/4096.f) + 1e-5f);
  const float4* s1v = (const float4*)sc1;
  float4* ho = (float4*)(hout + (size_t)row*D_MODEL);
  float4 h4[4]; float ss2 = 0.f;
#pragma unroll
  for (int i=0;i<4;i++){
    float4 b4 = br[tid + i*256];
    float4 s4 = s1v[tid + i*256];
    float4 h;
    h.x = b4.x + d[i].x*inv1*s4.x;
    h.y = b4.y + d[i].y*inv1*s4.y;
    h.z = b4.z + d[i].z*inv1*s4.z;
    h.w = b4.w + d[i].w*inv1*s4.w;
    h4[i] = h;
    ho[tid + i*256] = h;
    ss2 += h.x*h.x + h.y*h.y + h.z*h.z + h.w*h.w;
  }
  if (sc2){
#pragma unroll
    for (int m=32;m;m>>=1) ss2 += __shfl_xor(ss2, m);
    __syncthreads();
    if ((tid&63)==0) red[tid>>6] = ss2;
    __syncthreads();
    float inv2 = rsqrtf((red[0]+red[1]+red[2]+red[3])*(1.f/4096.f) + 1e-5f);
    const float4* s2v = (const float4*)sc2;
#pragma unroll
    for (int i=0;i<4;i++){
      float4 s4 = s2v[tid + i*256];
      ushort4 o;
      o.x = f2bf(h4[i].x*inv2*s4.x); o.y = f2bf(h4[i].y*inv2*s4.y);
      o.z = f2bf(h4[i].z*inv2*s4.z); o.w = f2bf(h4[i].w*inv2*s4.w);
      ((ushort4*)hn2)[(size_t)row*1024 + tid + i*256] = o;
    }
  }
}

// ------- weight convert+transpose: WT[n][k] = (k<K && n<N) ? W[k][n] : 0, bf16 -------
__global__ __launch_bounds__(256) void convT(const float* __restrict__ W,
                                             ushort_t* __restrict__ WT,
                                             int K, int N, int Kp, int Np){
  __shared__ float tile[64][69];     // pad 69: write-phase kc-lanes spread banks
  int tx = threadIdx.x & 15, ty = threadIdx.x >> 4;      // read: 16 n-float4 x 16 k
  int n0 = blockIdx.x*64, k0 = blockIdx.y*64;
#pragma unroll
  for (int i=0;i<4;i++){
    int k = k0 + ty + i*16, n = n0 + tx*4;
    float4 v;
    if (k < K && n + 3 < N){
      v = *(const float4*)&W[(size_t)k*N + n];
    } else {
      v.x = (k<K && n+0<N) ? W[(size_t)k*N + n+0] : 0.f;
      v.y = (k<K && n+1<N) ? W[(size_t)k*N + n+1] : 0.f;
      v.z = (k<K && n+2<N) ? W[(size_t)k*N + n+2] : 0.f;
      v.w = (k<K && n+3<N) ? W[(size_t)k*N + n+3] : 0.f;
    }
    tile[ty+i*16][tx*4+0] = v.x;
    tile[ty+i*16][tx*4+1] = v.y;
    tile[ty+i*16][tx*4+2] = v.z;
    tile[ty+i*16][tx*4+3] = v.w;
  }
  __syncthreads();
  int kc = (threadIdx.x & 7)*8, nr = threadIdx.x >> 3;   // write: 8 k-chunks x 32 n
#pragma unroll
  for (int j=0;j<2;j++){
    int n = n0 + nr + j*32;
    if (n < Np){
      us8 o;
#pragma unroll
      for (int i=0;i<8;i++) o[i] = f2bf(tile[kc+i][nr + j*32]);
      *(us8*)&WT[(size_t)n*Kp + k0 + kc] = o;
    }
  }
}

// ====== 256xBN wide-wave GEMM (R8 schedule, measured best): C = A @ WT^T (bf16) ======
template<int MODE, int KS, int CF>
__global__ __launch_bounds__(512, 2) void gemmW(const ushort_t* __restrict__ A, int lda,
                                                const ushort_t* __restrict__ WT, int ldw,
                                                void* __restrict__ Cv, void* __restrict__ Cv2,
                                                int ldc, int Nvalid, int K){
  constexpr int BN   = CF*32;
  constexpr int NCH  = 4 + CF/2;              // stage chunks per K-tile
  constexpr int SLOT = 32768 + (CF/2)*8192;
  __shared__ __align__(16) char smem[2*SLOT];
  const int nwg = gridDim.x;
  const int lid = blockIdx.x;
  int t = (lid & 7) * (nwg >> 3) + (lid >> 3);          // bijective XCD chunking
  void* Cout = Cv;
  if (KS == 2){
    const int per = nwg >> 1;
    if (t >= per){ t -= per; A += (size_t)K; WT += (size_t)K; Cout = Cv2; }
  }
  const int m0 = (t & 7) << 8;                          // 8 m-tiles (M=2048), m fastest
  const int n0 = (t >> 3) * BN;
  const int tid = threadIdx.x;
  const int w = tid >> 6, lane = tid & 63;
  const int wm = w >> 1, wn = w & 1;                    // wave tile 64(M) x CF*16(N)
  const int lo = lane & 15, hi = lane >> 4;
  const int srow = lane >> 3, scol = lane & 7;
  const int sw = scol ^ srow;                           // pre-swizzled source k-chunk
  const int rsw = lo & 7;
  const int NT = K >> 6;

  const ushort_t* pA = A  + (size_t)(m0 + w*8 + srow) * lda + sw*8;
  const ushort_t* pB = WT + (size_t)(n0 + w*8 + srow) * ldw + sw*8;

  auto stage = [&](int tt, int c){
    const ushort_t* g = (c < 4 ? pA + (size_t)(c*64)*lda : pB + (size_t)((c-4)*64)*ldw) + (size_t)tt*64;
    g2lds16(smem + (tt&1)*SLOT + (c < 4 ? c*8192 : 32768 + (c-4)*8192) + (w<<10), g);
  };

  f32x4 acc[4][CF];
#pragma unroll
  for (int i=0;i<4;i++)
#pragma unroll
    for (int j=0;j<CF;j++) acc[i][j] = zero4();

#pragma unroll
  for (int c=0;c<NCH;c++) stage(0, c);
#pragma unroll
  for (int c=0;c<NCH;c++) stage(1, c);

  for (int i=0;i<NT;i++){
    if (i == NT-1) { VMCNT0(); }
    else if (CF == 8) { VMCNT8(); } else { VMCNT7(); }  // tile i fully landed
    BAR();
    const char* sA = smem + (i&1)*SLOT;
    const char* sB = sA + 32768;
    bf16x8 af[4][2], bfr[CF][2];
#pragma unroll
    for (int rf=0;rf<4;rf++)
#pragma unroll
      for (int kc=0;kc<2;kc++)
        af[rf][kc] = ldb8(sA + (wm*64 + rf*16 + lo)*128 + (((kc*4+hi)^rsw)<<4));
#pragma unroll
    for (int cf=0;cf<CF;cf++)
#pragma unroll
      for (int kc=0;kc<2;kc++)
        bfr[cf][kc] = ldb8(sB + (wn*(CF*16) + cf*16 + lo)*128 + (((kc*4+hi)^rsw)<<4));
    LGKM0();          // all slot reads retired before stage writes can land
    BAR();
    if (i+2 < NT){
#pragma unroll
      for (int c=0;c<NCH;c++) stage(i+2, c);   // into slot (i+2)&1 == i&1 (just read)
    }
#pragma unroll
    for (int rf=0;rf<4;rf++)
#pragma unroll
      for (int cf=0;cf<CF;cf++)
#pragma unroll
        for (int kc=0;kc<2;kc++)
          acc[rf][cf] = MFMA(af[rf][kc], bfr[cf][kc], acc[rf][cf]);
  }
  // epilogue
#pragma unroll
  for (int rf=0;rf<4;rf++){
#pragma unroll
    for (int cf=0;cf<CF;cf++){
#pragma unroll
      for (int r=0;r<4;r++){
        int m = m0 + wm*64 + rf*16 + hi*4 + r;
        int n = n0 + wn*(CF*16) + cf*16 + lo;
        if (n < Nvalid){
          float v = acc[rf][cf][r];
          size_t idx = (size_t)m*ldc + n;
          if (MODE == 1) ((float*)Cout)[idx] = v;
          else           ((ushort_t*)Cout)[idx] = f2bf(v);
        }
      }
    }
  }
}

// ====== gemmS: 256x128 BK=32, 2 blocks/CU, PHASE-STAGGERED: C = A @ WT^T ======
// R12 kernel verbatim + one-time ~1536-cyc s_sleep on the CU's second block
// (blockIdx&256) to break phase-lock so one block's LDS-read phase overlaps the
// co-resident block's MFMA phase (m114 TLP). Sleep placed after prologue stage
// issue so the DMA lands during the sleep.
template<int MODE, int KS>
__global__ __launch_bounds__(512, 4) void gemmS(const ushort_t* __restrict__ A, int lda,
                                                const ushort_t* __restrict__ WT, int ldw,
                                                void* __restrict__ Cv, void* __restrict__ Cv2,
                                                int ldc, int Nvalid, int K){
  __shared__ __align__(16) char smem[49152];            // 2 x 24KB
  const int nwg = gridDim.x;
  const int lid = blockIdx.x;
  int t = (lid & 7) * (nwg >> 3) + (lid >> 3);          // bijective XCD chunking
  void* Cout = Cv;
  if (KS == 2){
    const int per = nwg >> 1;
    if (t >= per){ t -= per; A += (size_t)K; WT += (size_t)K; Cout = Cv2; }
  }
  const int m0 = (t & 7) << 8;                          // 8 m-tiles (M=2048), m fastest
  const int n0 = (t >> 3) << 7;                         // BN=128
  const int tid = threadIdx.x;
  const int w = tid >> 6, lane = tid & 63;
  const int wm = w >> 1, wn = w & 1;                    // wave tile 64 x 64
  const int lo = lane & 15, hi = lane >> 4;
  const int rsw2 = (lo >> 1) & 3;
  const int strow = tid >> 2;                           // 0..127 (chunk row)
  const int sseg  = (tid & 3) ^ ((tid >> 3) & 3);       // pre-swizzled k-seg
  const int NT = K >> 5;

  // chunks: 0,1 = A rows c*128+strow ; 2 = B rows strow. 8KB per chunk.
  auto stage = [&](int tt, int c){
    const ushort_t* g;
    int lofs;
    if (c < 2){ g = A  + (size_t)(m0 + c*128 + strow)*lda; lofs = c*8192; }
    else      { g = WT + (size_t)(n0 + strow)*ldw;         lofs = 16384; }
    g2lds16(smem + (tt&1)*24576 + lofs + (w<<10),
            g + (size_t)tt*32 + sseg*8);
  };

  f32x4 acc[4][4];
#pragma unroll
  for (int i=0;i<4;i++)
#pragma unroll
    for (int j=0;j<4;j++) acc[i][j] = zero4();

#pragma unroll
  for (int c=0;c<3;c++) stage(0, c);
#pragma unroll
  for (int c=0;c<3;c++) stage(1, c);

  if (blockIdx.x & 256) __builtin_amdgcn_s_sleep(24);   // ~1536 cyc de-phase stagger

  for (int i=0;i<NT;i++){
    if (i == NT-1) VMCNT0(); else VMCNT3();   // tile i fully landed
    BAR();
    const char* sA = smem + (i&1)*24576;
    const char* sB = sA + 16384;
    bf16x8 af[4], bfr[4];
#pragma unroll
    for (int rf=0;rf<4;rf++)
      af[rf] = ldb8(sA + (wm*64 + rf*16 + lo)*64 + ((hi^rsw2)<<4));
#pragma unroll
    for (int cf=0;cf<4;cf++)
      bfr[cf] = ldb8(sB + (wn*64 + cf*16 + lo)*64 + ((hi^rsw2)<<4));
    LGKM0();          // all slot reads retired before stage writes can land
    BAR();
    if (i+2 < NT){
      stage(i+2, 0); stage(i+2, 1); stage(i+2, 2);   // slot (i+2)&1 == i&1 (just read)
    }
#pragma unroll
    for (int rf=0;rf<4;rf++)
#pragma unroll
      for (int cf=0;cf<4;cf++)
        acc[rf][cf] = MFMA(af[rf], bfr[cf], acc[rf][cf]);
  }
  // epilogue
#pragma unroll
  for (int rf=0;rf<4;rf++){
#pragma unroll
    for (int cf=0;cf<4;cf++){
#pragma unroll
      for (int r=0;r<4;r++){
        int m = m0 + wm*64 + rf*16 + hi*4 + r;
        int n = n0 + wn*64 + cf*16 + lo;
        if (n < Nvalid){
          float v = acc[rf][cf][r];
          size_t idx = (size_t)m*ldc + n;
          if (MODE == 1) ((float*)Cout)[idx] = v;
          else           ((ushort_t*)Cout)[idx] = f2bf(v);
        }
      }
    }
  }
}

// ===== fused gate+val GEMM (R8 schedule): act = gelu(A@Wg^T) * (A@Wv^T), bf16 out =====
__global__ __launch_bounds__(512, 2) void gemm_gv(const ushort_t* __restrict__ A, int lda,
                                                  const ushort_t* __restrict__ B1,
                                                  const ushort_t* __restrict__ B2, int ldw,
                                                  ushort_t* __restrict__ Cv, int ldc,
                                                  int Nvalid, int K){
  __shared__ __align__(16) char smem[131072];           // 2 x 64KB
  const int nwg = gridDim.x;
  const int lid = blockIdx.x;
  const int t  = (lid & 7) * (nwg >> 3) + (lid >> 3);
  const int m0 = (t & 7) << 8;
  const int n0 = (t >> 3) << 7;
  const int tid = threadIdx.x;
  const int w = tid >> 6, lane = tid & 63;
  const int wm = w >> 1, wn = w & 1;
  const int lo = lane & 15, hi = lane >> 4;
  const int srow = lane >> 3, scol = lane & 7;
  const int sw = scol ^ srow;
  const int rsw = lo & 7;
  const int NT = K >> 6;

  const ushort_t* pA  = A  + (size_t)(m0 + w*8 + srow) * lda + sw*8;
  const ushort_t* pB1 = B1 + (size_t)(n0 + w*8 + srow) * ldw + sw*8;
  const ushort_t* pB2 = B2 + (size_t)(n0 + w*8 + srow) * ldw + sw*8;

  auto stage = [&](int tt, int c){
    const ushort_t* g;
    int lofs;
    if (c < 4){ g = pA  + (size_t)(c*64)*lda;     lofs = c*8192; }
    else if (c < 6){ g = pB1 + (size_t)((c-4)*64)*ldw; lofs = 32768 + (c-4)*8192; }
    else { g = pB2 + (size_t)((c-6)*64)*ldw; lofs = 49152 + (c-6)*8192; }
    g2lds16(smem + ((tt&1)<<16) + lofs + (w<<10), g + (size_t)tt*64);
  };

  f32x4 ag[4][4], av[4][4];
#pragma unroll
  for (int i=0;i<4;i++)
#pragma unroll
    for (int j=0;j<4;j++){ ag[i][j] = zero4(); av[i][j] = zero4(); }

#pragma unroll
  for (int c=0;c<8;c++) stage(0, c);
#pragma unroll
  for (int c=0;c<8;c++) stage(1, c);

  for (int i=0;i<NT;i++){
    if (i == NT-1) VMCNT0(); else VMCNT8();   // tile i fully landed
    BAR();
    const char* sA  = smem + ((i&1)<<16);
    const char* sB1 = sA + 32768;
    const char* sB2 = sA + 49152;
    bf16x8 af[4][2], b1f[4][2], b2f[4][2];
#pragma unroll
    for (int rf=0;rf<4;rf++)
#pragma unroll
      for (int kc=0;kc<2;kc++)
        af[rf][kc] = ldb8(sA + (wm*64 + rf*16 + lo)*128 + (((kc*4+hi)^rsw)<<4));
#pragma unroll
    for (int cf=0;cf<4;cf++)
#pragma unroll
      for (int kc=0;kc<2;kc++){
        b1f[cf][kc] = ldb8(sB1 + (wn*64 + cf*16 + lo)*128 + (((kc*4+hi)^rsw)<<4));
        b2f[cf][kc] = ldb8(sB2 + (wn*64 + cf*16 + lo)*128 + (((kc*4+hi)^rsw)<<4));
      }
    LGKM0();          // all slot-cur reads retired before stage writes can land
    BAR();
    if (i+2 < NT){
#pragma unroll
      for (int c=0;c<8;c++) stage(i+2, c);   // into slot (i+2)&1 == i&1 (just read)
    }
#pragma unroll
    for (int rf=0;rf<4;rf++)
#pragma unroll
      for (int cf=0;cf<4;cf++)
#pragma unroll
        for (int kc=0;kc<2;kc++){
          ag[rf][cf] = MFMA(af[rf][kc], b1f[cf][kc], ag[rf][cf]);
          av[rf][cf] = MFMA(af[rf][kc], b2f[cf][kc], av[rf][cf]);
        }
  }
  // epilogue: act = gelu(G) * V, fp32 internal, one bf16 rounding
#pragma unroll
  for (int rf=0;rf<4;rf++){
#pragma unroll
    for (int cf=0;cf<4;cf++){
#pragma unroll
      for (int r=0;r<4;r++){
        int m = m0 + wm*64 + rf*16 + hi*4 + r;
        int n = n0 + wn*64 + cf*16 + lo;
        if (n < Nvalid){
          float g = ag[rf][cf][r];
          float v = av[rf][cf][r];
          float ga = 0.5f*g*(1.f + tanhf(0.7978845608028654f*(g + 0.044715f*g*g*g)));
          Cv[(size_t)m*ldc + n] = f2bf(ga * v);
        }
      }
    }
  }
}

// ---------------- RoPE ----------------
__global__ void rope_tab_kernel(float* __restrict__ tab){
  int s = blockIdx.x, i = threadIdx.x;             // s<1024, i<64
  float invf = __expf(-(float)i * (9.210340371976184f/64.f));  // 10000^(-i/64)
  float ph = (float)s * invf;
  float sn, cs;
  sincosf(ph, &sn, &cs);
  tab[s*128 + i] = cs;
  tab[s*128 + 64 + i] = sn;
}

__global__ __launch_bounds__(256) void rope_apply(ushort_t* __restrict__ qkv,
                                                  const float* __restrict__ tab){
  int idx = blockIdx.x*256 + threadIdx.x;          // 2048*40*64 total
  int pr = idx & 63;
  int h  = (idx >> 6) % 40;                        // 32 q heads + 8 k heads
  int row = idx / 2560;
  int t = row & (SEQ-1);
  ushort_t* p = qkv + (size_t)row*QKV_N + h*HD + pr;
  float c = tab[t*128 + pr], s = tab[t*128 + 64 + pr];
  float x1 = bf2f(p[0]), x2 = bf2f(p[64]);
  p[0]  = f2bf(x1*c - x2*s);
  p[64] = f2bf(x2*c + x1*s);
}

// ---------------- V transpose: VT[d][m] = qkv[m][5120+d] ----------------
__global__ __launch_bounds__(256) void transpose_v(const ushort_t* __restrict__ qkv,
                                                   ushort_t* __restrict__ VT){
  __shared__ ushort_t tile[32][33];
  int d0 = blockIdx.x*32, m0 = blockIdx.y*32;
  int tx = threadIdx.x & 31, ty = threadIdx.x >> 5;
#pragma unroll
  for (int i=0;i<4;i++)
    tile[ty + i*8][tx] = qkv[(size_t)(m0 + ty + i*8)*QKV_N + 5120 + d0 + tx];
  __syncthreads();
#pragma unroll
  for (int i=0;i<4;i++)
    VT[(size_t)(d0 + ty + i*8)*BROWS + m0 + tx] = tile[tx][ty + i*8];
}

// ---------------- Flash attention with tanh soft-cap, GQA, causal ----------------
__global__ __launch_bounds__(256) void attn_kernel(const ushort_t* __restrict__ qkv,
                                                   const ushort_t* __restrict__ VT,
                                                   ushort_t* __restrict__ outp){
  const int blk = blockIdx.x;
  const int bh = blk & 63;
  const int tgrp = 15 - (blk >> 6);     // heavy tiles dispatched first
  const int b = bh >> 5, qh = bh & 31, kv = qh >> 2;
  const int w = threadIdx.x >> 6, lane = threadIdx.x & 63;
  const int lo = lane & 15, hi = lane >> 4;
  const int t0 = tgrp*64 + w*16;
  __shared__ ushort_t P[4][16][72];     // per-wave P transpose buffer
  ushort_t (*Pw)[72] = P[w];

  const ushort_t* Qb = qkv + (size_t)(b*SEQ + t0 + lo)*QKV_N + qh*HD + hi*8;
  bf16x8 qf[4];
#pragma unroll
  for (int c=0;c<4;c++) qf[c] = ldb8(Qb + c*32);

  f32x4 of[8];
#pragma unroll
  for (int i=0;i<8;i++) of[i] = zero4();
  float ls[4] = {0.f,0.f,0.f,0.f};

  const ushort_t* Kb = qkv + (size_t)(b*SEQ + lo)*QKV_N + D_MODEL + kv*HD + hi*8;
  const ushort_t* Vb = VT + (size_t)(kv*HD + lo)*BROWS + b*SEQ + hi*8;

  const int nst = tgrp + 1;
  for (int st=0; st<nst; st++){
    const int s0 = st*64;
    f32x4 sacc[4];
#pragma unroll
    for (int nf=0;nf<4;nf++) sacc[nf] = zero4();
#pragma unroll
    for (int c=0;c<4;c++){
#pragma unroll
      for (int nf=0;nf<4;nf++){
        bf16x8 kf = ldb8(Kb + (size_t)(s0 + nf*16)*QKV_N + c*32);
        sacc[nf] = MFMA(qf[c], kf, sacc[nf]);
      }
    }
    // softmax (fixed max = 30 thanks to tanh cap) + write P^T to LDS
#pragma unroll
    for (int nf=0;nf<4;nf++){
#pragma unroll
      for (int r=0;r<4;r++){
        int tq = t0 + hi*4 + r;
        int s = s0 + nf*16 + lo;
        float xx = sacc[nf][r] * ATTN_MULT;
        float z = fminf(fmaxf(xx*(2.f/30.f), -80.f), 80.f);
        float e = __expf(z);
        float th = (e - 1.f)/(e + 1.f);
        float p = (s <= tq) ? __expf(30.f*th - 30.f) : 0.f;
        ls[r] += p;
        Pw[hi*4+r][nf*16+lo] = f2bf(p);
      }
    }
    __builtin_amdgcn_sched_barrier(0);
    __builtin_amdgcn_s_waitcnt(0xc07f);   // lgkmcnt(0): P writes visible wave-wide
    __builtin_amdgcn_sched_barrier(0);
#pragma unroll
    for (int c2=0;c2<2;c2++){
      bf16x8 pf = ldb8(&Pw[lo][c2*32 + hi*8]);
#pragma unroll
      for (int nf2=0;nf2<8;nf2++){
        bf16x8 vf = ldb8(Vb + (size_t)(nf2*16)*BROWS + s0 + c2*32);
        of[nf2] = MFMA(pf, vf, of[nf2]);
      }
    }
    __builtin_amdgcn_sched_barrier(0);
  }
#pragma unroll
  for (int m=1;m<16;m<<=1){
#pragma unroll
    for (int r=0;r<4;r++) ls[r] += __shfl_xor(ls[r], m);
  }
  float inv[4];
#pragma unroll
  for (int r=0;r<4;r++) inv[r] = 1.f/ls[r];
  ushort_t* Ob = outp + (size_t)(b*SEQ + t0 + hi*4)*D_MODEL + qh*HD + lo;
#pragma unroll
  for (int nf2=0;nf2<8;nf2++)
#pragma unroll
    for (int r=0;r<4;r++)
      Ob[(size_t)r*D_MODEL + nf2*16] = f2bf(of[nf2][r]*inv[r]);
}

// =============================== host launcher ===============================
extern "C" void kernel_launch(void* const* d_in, const int* in_sizes, int n_in,
                              void* d_out, int out_size, void* d_ws, size_t ws_size,
                              hipStream_t stream){
  const float* x        = (const float*)d_in[0];
  const float* sc_pre_a = (const float*)d_in[2];
  const float* sc_post_a= (const float*)d_in[3];
  const float* sc_pre_m = (const float*)d_in[4];
  const float* sc_post_m= (const float*)d_in[5];
  const float* wq  = (const float*)d_in[6];
  const float* wk  = (const float*)d_in[7];
  const float* wv  = (const float*)d_in[8];
  const float* wo  = (const float*)d_in[9];
  const float* wg  = (const float*)d_in[10];
  const float* wva = (const float*)d_in[11];
  const float* wou = (const float*)d_in[12];

  char* ws = (char*)d_ws;
  size_t off = 0;
  auto alloc = [&](size_t bytes)->void*{
    void* p = ws + off; off += (bytes + 255) & ~(size_t)255; return p;
  };
  ushort_t* WT   = (ushort_t*)alloc((size_t)FFN_GRID*D_MODEL*2); // reusable weight slot
  ushort_t* hn   = (ushort_t*)alloc((size_t)BROWS*D_MODEL*2);
  ushort_t* qkv  = (ushort_t*)alloc((size_t)BROWS*QKV_N*2);
  ushort_t* VT   = (ushort_t*)alloc((size_t)SEQ*BROWS*2);
  ushort_t* attn = (ushort_t*)alloc((size_t)BROWS*D_MODEL*2);
  float*    tmp32= (float*)alloc((size_t)BROWS*D_MODEL*4);
  ushort_t* hn2  = (ushort_t*)alloc((size_t)BROWS*D_MODEL*2);
  ushort_t* act  = (ushort_t*)alloc((size_t)BROWS*FFN_GRID*2);
  float*    rtab = (float*)alloc((size_t)SEQ*128*4);
  float* h = (float*)d_out;
  // WT2 (90.2 MB) overlays [hn .. tmp32] (96.5 MB) — all dead when gate/val runs.
  ushort_t* WT2  = (ushort_t*)hn;
  // split-K slice-1 partials reuse dead regions (no ws growth):
  float* part_o  = (float*)act;   // act free until gv writes it (after step 9)
  float* part_u  = (float*)hn;    // hn+qkv dead after attention; WT2 dead after gv

  // 1. pre-attn norm
  rmsnorm_in<<<BROWS, 256, 0, stream>>>(x, sc_pre_a, hn);
  // 2. convert wq|wk|wv -> WT[6144][4096]
  convT<<<dim3(64, 64), 256, 0, stream>>>(wq, WT,                     4096, 4096, 4096, 4096);
  convT<<<dim3(16, 64), 256, 0, stream>>>(wk, WT + (size_t)4096*4096, 4096, 1024, 4096, 1024);
  convT<<<dim3(16, 64), 256, 0, stream>>>(wv, WT + (size_t)5120*4096, 4096, 1024, 4096, 1024);
  // 3. fused QKV GEMM (BN=192: 8 m x 32 n = 256 blocks, 100% fill)
  gemmW<0,1,6><<<256, 512, 0, stream>>>(hn, 4096, WT, 4096, qkv, nullptr, QKV_N, QKV_N, 4096);
  // 4. RoPE on q,k
  rope_tab_kernel<<<SEQ, 64, 0, stream>>>(rtab);
  rope_apply<<<(BROWS*40*64)/256, 256, 0, stream>>>(qkv, rtab);
  // 5. V transpose for PV B-operand
  transpose_v<<<dim3(32,64), 256, 0, stream>>>(qkv, VT);
  // 6. attention
  attn_kernel<<<1024, 256, 0, stream>>>(qkv, VT, attn);
  // 7-8. O projection, split-K x2, STAGGERED 2-blocks/CU (512 blocks)
  convT<<<dim3(64, 64), 256, 0, stream>>>(wo, WT, 4096, 4096, 4096, 4096);
  gemmS<1,2><<<512, 512, 0, stream>>>(attn, 4096, WT, 4096, tmp32, part_o, 4096, 4096, 2048);
  // 9. h = x + rms(o0+o1)*sc ; hn2 = rms(h)*sc_pre_mlp
  rmsnorm_resid<<<BROWS, 256, 0, stream>>>(x, tmp32, part_o, sc_post_a, h, sc_pre_m, hn2);
  // 10. convert wg -> WT, wva -> WT2
  convT<<<dim3(172, 64), 256, 0, stream>>>(wg,  WT,  4096, 10928, 4096, FFN_GRID);
  convT<<<dim3(172, 64), 256, 0, stream>>>(wva, WT2, 4096, 10928, 4096, FFN_GRID);
  // 11. fused gate+val GEMM (8 x 86 = 688 blocks): act = gelu(A@Wg^T) * (A@Wv^T)
  gemm_gv<<<688, 512, 0, stream>>>(hn2, 4096, WT, WT2, 4096, act, FFN_GRID, FFN_GRID, 4096);
  // 12-13. out projection: K padded to 11008, split-K x2, STAGGERED (512 blocks)
  convT<<<dim3(64, 172), 256, 0, stream>>>(wou, WT, 10928, 4096, FFN_GRID, 4096);
  gemmS<1,2><<<512, 512, 0, stream>>>(act, FFN_GRID, WT, FFN_GRID, tmp32, part_u, 4096, 4096, 5504);
  // 14. final residual + norm (in-place on d_out)
  rmsnorm_resid<<<BROWS, 256, 0, stream>>>(h, tmp32, part_u, sc_post_m, h, nullptr, nullptr);
}

// Round 15
// 1104.923 us; speedup vs baseline: 1.0711x; 1.0711x over previous
//
#include <hip/hip_runtime.h>
#include <stdint.h>

typedef unsigned short ushort_t;
typedef unsigned short us8 __attribute__((ext_vector_type(8)));
typedef __bf16 bf16x8 __attribute__((ext_vector_type(8)));
typedef float f32x4 __attribute__((ext_vector_type(4)));

#define D_MODEL 4096
#define SEQ 1024
#define BROWS 2048
#define QKV_N 6144
#define HD 128
#define FFN_GRID 11008
#define ATTN_MULT 0.08838834764831845f

__device__ __forceinline__ unsigned short f2bf(float f){
  union { float f; unsigned u; } c; c.f = f;
  unsigned u = c.u + 0x7fffu + ((c.u >> 16) & 1u);
  return (unsigned short)(u >> 16);
}
__device__ __forceinline__ float bf2f(unsigned short h){
  union { unsigned u; float f; } c; c.u = ((unsigned)h) << 16;
  return c.f;
}
__device__ __forceinline__ f32x4 zero4(){ f32x4 z; z[0]=0.f; z[1]=0.f; z[2]=0.f; z[3]=0.f; return z; }
__device__ __forceinline__ bf16x8 ldb8(const void* p){ return *(const bf16x8*)p; }
__device__ __forceinline__ f32x4 MFMA(bf16x8 a, bf16x8 b, f32x4 c){
  return __builtin_amdgcn_mfma_f32_16x16x32_bf16(a, b, c, 0, 0, 0);
}
// async global->LDS, 16B per lane; LDS dest = wave-uniform base + lane*16
__device__ __forceinline__ void g2lds16(void* lds, const void* g){
  __builtin_amdgcn_global_load_lds(
      (const __attribute__((address_space(1))) void*)(uintptr_t)(g),
      (__attribute__((address_space(3))) void*)(uint32_t)(uintptr_t)(lds),
      16, 0, 0);
}
#define BAR() __builtin_amdgcn_s_barrier()
#define VMCNT8() asm volatile("s_waitcnt vmcnt(8)" ::: "memory")
#define VMCNT7() asm volatile("s_waitcnt vmcnt(7)" ::: "memory")
#define VMCNT0() asm volatile("s_waitcnt vmcnt(0)" ::: "memory")
#define LGKM0() asm volatile("s_waitcnt lgkmcnt(0)" ::: "memory")

// ---------------- RMSNorm (input) : hn = rms(x)*scale, bf16 out ----------------
__global__ __launch_bounds__(256) void rmsnorm_in(const float* __restrict__ x,
                                                  const float* __restrict__ sc,
                                                  ushort_t* __restrict__ out){
  int row = blockIdx.x, tid = threadIdx.x;
  const float4* xr = (const float4*)(x + (size_t)row*D_MODEL);
  float4 v[4]; float ss = 0.f;
#pragma unroll
  for (int i=0;i<4;i++){
    v[i] = xr[tid + i*256];
    ss += v[i].x*v[i].x + v[i].y*v[i].y + v[i].z*v[i].z + v[i].w*v[i].w;
  }
#pragma unroll
  for (int m=32;m;m>>=1) ss += __shfl_xor(ss, m);
  __shared__ float red[4];
  if ((tid&63)==0) red[tid>>6] = ss;
  __syncthreads();
  float inv = rsqrtf((red[0]+red[1]+red[2]+red[3])*(1.f/4096.f) + 1e-5f);
  const float4* scv = (const float4*)sc;
#pragma unroll
  for (int i=0;i<4;i++){
    float4 s4 = scv[tid + i*256];
    ushort4 o;
    o.x = f2bf(v[i].x*inv*s4.x); o.y = f2bf(v[i].y*inv*s4.y);
    o.z = f2bf(v[i].z*inv*s4.z); o.w = f2bf(v[i].w*inv*s4.w);
    ((ushort4*)out)[(size_t)row*1024 + tid + i*256] = o;
  }
}

// ---- residual+norm: h = base + rms(delta [+ delta2])*sc1 ; opt hn2 = rms(h)*sc2 ----
__global__ __launch_bounds__(256) void rmsnorm_resid(const float* __restrict__ base,
                                                     const float* __restrict__ delta,
                                                     const float* __restrict__ delta2,
                                                     const float* __restrict__ sc1,
                                                     float* __restrict__ hout,
                                                     const float* __restrict__ sc2,
                                                     ushort_t* __restrict__ hn2){
  int row = blockIdx.x, tid = threadIdx.x;
  const float4* dr = (const float4*)(delta + (size_t)row*D_MODEL);
  const float4* d2 = delta2 ? (const float4*)(delta2 + (size_t)row*D_MODEL) : nullptr;
  const float4* br = (const float4*)(base  + (size_t)row*D_MODEL);
  float4 d[4]; float ss = 0.f;
#pragma unroll
  for (int i=0;i<4;i++){
    float4 a = dr[tid + i*256];
    if (d2){
      float4 b = d2[tid + i*256];
      a.x += b.x; a.y += b.y; a.z += b.z; a.w += b.w;
    }
    d[i] = a;
    ss += d[i].x*d[i].x + d[i].y*d[i].y + d[i].z*d[i].z + d[i].w*d[i].w;
  }
#pragma unroll
  for (int m=32;m;m>>=1) ss += __shfl_xor(ss, m);
  __shared__ float red[4];
  if ((tid&63)==0) red[tid>>6] = ss;
  __syncthreads();
  float inv1 = rsqrtf((red[0]+red[1]+red[2]+red[3])*(1.f/4096.f) + 1e-5f);
  const float4* s1v = (const float4*)sc1;
  float4* ho = (float4*)(hout + (size_t)row*D_MODEL);
  float4 h4[4]; float ss2 = 0.f;
#pragma unroll
  for (int i=0;i<4;i++){
    float4 b4 = br[tid + i*256];
    float4 s4 = s1v[tid + i*256];
    float4 h;
    h.x = b4.x + d[i].x*inv1*s4.x;
    h.y = b4.y + d[i].y*inv1*s4.y;
    h.z = b4.z + d[i].z*inv1*s4.z;
    h.w = b4.w + d[i].w*inv1*s4.w;
    h4[i] = h;
    ho[tid + i*256] = h;
    ss2 += h.x*h.x + h.y*h.y + h.z*h.z + h.w*h.w;
  }
  if (sc2){
#pragma unroll
    for (int m=32;m;m>>=1) ss2 += __shfl_xor(ss2, m);
    __syncthreads();
    if ((tid&63)==0) red[tid>>6] = ss2;
    __syncthreads();
    float inv2 = rsqrtf((red[0]+red[1]+red[2]+red[3])*(1.f/4096.f) + 1e-5f);
    const float4* s2v = (const float4*)sc2;
#pragma unroll
    for (int i=0;i<4;i++){
      float4 s4 = s2v[tid + i*256];
      ushort4 o;
      o.x = f2bf(h4[i].x*inv2*s4.x); o.y = f2bf(h4[i].y*inv2*s4.y);
      o.z = f2bf(h4[i].z*inv2*s4.z); o.w = f2bf(h4[i].w*inv2*s4.w);
      ((ushort4*)hn2)[(size_t)row*1024 + tid + i*256] = o;
    }
  }
}

// ------- weight convert+transpose: WT[n][k] = (k<K && n<N) ? W[k][n] : 0, bf16 -------
// 64k x 64n tile. Reads: float4 (16B/lane, coalesced along n). Writes: each n-row's
// 64 k-values (128B) produced by 8 lanes x ushort8 (16B) = fully coalesced.
__global__ __launch_bounds__(256) void convT(const float* __restrict__ W,
                                             ushort_t* __restrict__ WT,
                                             int K, int N, int Kp, int Np){
  __shared__ float tile[64][69];     // pad 69: write-phase kc-lanes spread banks
  int tx = threadIdx.x & 15, ty = threadIdx.x >> 4;      // read: 16 n-float4 x 16 k
  int n0 = blockIdx.x*64, k0 = blockIdx.y*64;
#pragma unroll
  for (int i=0;i<4;i++){
    int k = k0 + ty + i*16, n = n0 + tx*4;
    float4 v;
    if (k < K && n + 3 < N){
      v = *(const float4*)&W[(size_t)k*N + n];
    } else {
      v.x = (k<K && n+0<N) ? W[(size_t)k*N + n+0] : 0.f;
      v.y = (k<K && n+1<N) ? W[(size_t)k*N + n+1] : 0.f;
      v.z = (k<K && n+2<N) ? W[(size_t)k*N + n+2] : 0.f;
      v.w = (k<K && n+3<N) ? W[(size_t)k*N + n+3] : 0.f;
    }
    tile[ty+i*16][tx*4+0] = v.x;
    tile[ty+i*16][tx*4+1] = v.y;
    tile[ty+i*16][tx*4+2] = v.z;
    tile[ty+i*16][tx*4+3] = v.w;
  }
  __syncthreads();
  int kc = (threadIdx.x & 7)*8, nr = threadIdx.x >> 3;   // write: 8 k-chunks x 32 n
#pragma unroll
  for (int j=0;j<2;j++){
    int n = n0 + nr + j*32;
    if (n < Np){
      us8 o;
#pragma unroll
      for (int i=0;i<8;i++) o[i] = f2bf(tile[kc+i][nr + j*32]);
      *(us8*)&WT[(size_t)n*Kp + k0 + kc] = o;
    }
  }
}

// ====== 256xBN wide-wave GEMM (R8 schedule, measured best): C = A @ WT^T (bf16) ======
// 512 thr, 8 waves 4M x 2N, wave tile 64 x (CF*16). BN = CF*32. LDS = 2 slots of
// (A 32K + B CF/2*8K). Per K-tile: vmcnt(NCH) [vmcnt(0) last] -> BAR -> frag reads ->
// LGKM0 -> BAR (reads retired) -> stage tile i+2 into just-read slot -> MFMAs.
// KS=2: split-K, slice 1 offsets A/WT by K and writes Cv2. MODE 0: bf16; 1: fp32.
template<int MODE, int KS, int CF>
__global__ __launch_bounds__(512, 2) void gemmW(const ushort_t* __restrict__ A, int lda,
                                                const ushort_t* __restrict__ WT, int ldw,
                                                void* __restrict__ Cv, void* __restrict__ Cv2,
                                                int ldc, int Nvalid, int K){
  constexpr int BN   = CF*32;
  constexpr int NCH  = 4 + CF/2;              // stage chunks per K-tile
  constexpr int SLOT = 32768 + (CF/2)*8192;
  __shared__ __align__(16) char smem[2*SLOT];
  const int nwg = gridDim.x;
  const int lid = blockIdx.x;
  int t = (lid & 7) * (nwg >> 3) + (lid >> 3);          // bijective XCD chunking
  void* Cout = Cv;
  if (KS == 2){
    const int per = nwg >> 1;
    if (t >= per){ t -= per; A += (size_t)K; WT += (size_t)K; Cout = Cv2; }
  }
  const int m0 = (t & 7) << 8;                          // 8 m-tiles (M=2048), m fastest
  const int n0 = (t >> 3) * BN;
  const int tid = threadIdx.x;
  const int w = tid >> 6, lane = tid & 63;
  const int wm = w >> 1, wn = w & 1;                    // wave tile 64(M) x CF*16(N)
  const int lo = lane & 15, hi = lane >> 4;
  const int srow = lane >> 3, scol = lane & 7;
  const int sw = scol ^ srow;                           // pre-swizzled source k-chunk
  const int rsw = lo & 7;
  const int NT = K >> 6;

  const ushort_t* pA = A  + (size_t)(m0 + w*8 + srow) * lda + sw*8;
  const ushort_t* pB = WT + (size_t)(n0 + w*8 + srow) * ldw + sw*8;

  // chunks: 0-3 A rows c*64; 4..NCH-1 B rows (c-4)*64
  auto stage = [&](int tt, int c){
    const ushort_t* g = (c < 4 ? pA + (size_t)(c*64)*lda : pB + (size_t)((c-4)*64)*ldw) + (size_t)tt*64;
    g2lds16(smem + (tt&1)*SLOT + (c < 4 ? c*8192 : 32768 + (c-4)*8192) + (w<<10), g);
  };

  f32x4 acc[4][CF];
#pragma unroll
  for (int i=0;i<4;i++)
#pragma unroll
    for (int j=0;j<CF;j++) acc[i][j] = zero4();

#pragma unroll
  for (int c=0;c<NCH;c++) stage(0, c);
#pragma unroll
  for (int c=0;c<NCH;c++) stage(1, c);

  for (int i=0;i<NT;i++){
    if (i == NT-1) { VMCNT0(); }
    else if (CF == 8) { VMCNT8(); } else { VMCNT7(); }  // tile i fully landed
    BAR();
    const char* sA = smem + (i&1)*SLOT;
    const char* sB = sA + 32768;
    bf16x8 af[4][2], bfr[CF][2];
#pragma unroll
    for (int rf=0;rf<4;rf++)
#pragma unroll
      for (int kc=0;kc<2;kc++)
        af[rf][kc] = ldb8(sA + (wm*64 + rf*16 + lo)*128 + (((kc*4+hi)^rsw)<<4));
#pragma unroll
    for (int cf=0;cf<CF;cf++)
#pragma unroll
      for (int kc=0;kc<2;kc++)
        bfr[cf][kc] = ldb8(sB + (wn*(CF*16) + cf*16 + lo)*128 + (((kc*4+hi)^rsw)<<4));
    LGKM0();          // all slot reads retired before stage writes can land
    BAR();
    if (i+2 < NT){
#pragma unroll
      for (int c=0;c<NCH;c++) stage(i+2, c);   // into slot (i+2)&1 == i&1 (just read)
    }
#pragma unroll
    for (int rf=0;rf<4;rf++)
#pragma unroll
      for (int cf=0;cf<CF;cf++)
#pragma unroll
        for (int kc=0;kc<2;kc++)
          acc[rf][cf] = MFMA(af[rf][kc], bfr[cf][kc], acc[rf][cf]);
  }
  // epilogue
#pragma unroll
  for (int rf=0;rf<4;rf++){
#pragma unroll
    for (int cf=0;cf<CF;cf++){
#pragma unroll
      for (int r=0;r<4;r++){
        int m = m0 + wm*64 + rf*16 + hi*4 + r;
        int n = n0 + wn*(CF*16) + cf*16 + lo;
        if (n < Nvalid){
          float v = acc[rf][cf][r];
          size_t idx = (size_t)m*ldc + n;
          if (MODE == 1) ((float*)Cout)[idx] = v;
          else           ((ushort_t*)Cout)[idx] = f2bf(v);
        }
      }
    }
  }
}

// ===== fused gate+val GEMM (R8 schedule): act = gelu(A@Wg^T) * (A@Wv^T), bf16 out =====
__global__ __launch_bounds__(512, 2) void gemm_gv(const ushort_t* __restrict__ A, int lda,
                                                  const ushort_t* __restrict__ B1,
                                                  const ushort_t* __restrict__ B2, int ldw,
                                                  ushort_t* __restrict__ Cv, int ldc,
                                                  int Nvalid, int K){
  __shared__ __align__(16) char smem[131072];           // 2 x 64KB
  const int nwg = gridDim.x;
  const int lid = blockIdx.x;
  const int t  = (lid & 7) * (nwg >> 3) + (lid >> 3);
  const int m0 = (t & 7) << 8;
  const int n0 = (t >> 3) << 7;
  const int tid = threadIdx.x;
  const int w = tid >> 6, lane = tid & 63;
  const int wm = w >> 1, wn = w & 1;
  const int lo = lane & 15, hi = lane >> 4;
  const int srow = lane >> 3, scol = lane & 7;
  const int sw = scol ^ srow;
  const int rsw = lo & 7;
  const int NT = K >> 6;

  const ushort_t* pA  = A  + (size_t)(m0 + w*8 + srow) * lda + sw*8;
  const ushort_t* pB1 = B1 + (size_t)(n0 + w*8 + srow) * ldw + sw*8;
  const ushort_t* pB2 = B2 + (size_t)(n0 + w*8 + srow) * ldw + sw*8;

  // chunks: 0-3 A rows c*64; 4-5 B1 rows (c-4)*64; 6-7 B2 rows (c-6)*64
  auto stage = [&](int tt, int c){
    const ushort_t* g;
    int lofs;
    if (c < 4){ g = pA  + (size_t)(c*64)*lda;     lofs = c*8192; }
    else if (c < 6){ g = pB1 + (size_t)((c-4)*64)*ldw; lofs = 32768 + (c-4)*8192; }
    else { g = pB2 + (size_t)((c-6)*64)*ldw; lofs = 49152 + (c-6)*8192; }
    g2lds16(smem + ((tt&1)<<16) + lofs + (w<<10), g + (size_t)tt*64);
  };

  f32x4 ag[4][4], av[4][4];
#pragma unroll
  for (int i=0;i<4;i++)
#pragma unroll
    for (int j=0;j<4;j++){ ag[i][j] = zero4(); av[i][j] = zero4(); }

#pragma unroll
  for (int c=0;c<8;c++) stage(0, c);
#pragma unroll
  for (int c=0;c<8;c++) stage(1, c);

  for (int i=0;i<NT;i++){
    if (i == NT-1) VMCNT0(); else VMCNT8();   // tile i fully landed
    BAR();
    const char* sA  = smem + ((i&1)<<16);
    const char* sB1 = sA + 32768;
    const char* sB2 = sA + 49152;
    bf16x8 af[4][2], b1f[4][2], b2f[4][2];
#pragma unroll
    for (int rf=0;rf<4;rf++)
#pragma unroll
      for (int kc=0;kc<2;kc++)
        af[rf][kc] = ldb8(sA + (wm*64 + rf*16 + lo)*128 + (((kc*4+hi)^rsw)<<4));
#pragma unroll
    for (int cf=0;cf<4;cf++)
#pragma unroll
      for (int kc=0;kc<2;kc++){
        b1f[cf][kc] = ldb8(sB1 + (wn*64 + cf*16 + lo)*128 + (((kc*4+hi)^rsw)<<4));
        b2f[cf][kc] = ldb8(sB2 + (wn*64 + cf*16 + lo)*128 + (((kc*4+hi)^rsw)<<4));
      }
    LGKM0();          // all slot-cur reads retired before stage writes can land
    BAR();
    if (i+2 < NT){
#pragma unroll
      for (int c=0;c<8;c++) stage(i+2, c);   // into slot (i+2)&1 == i&1 (just read)
    }
#pragma unroll
    for (int rf=0;rf<4;rf++)
#pragma unroll
      for (int cf=0;cf<4;cf++)
#pragma unroll
        for (int kc=0;kc<2;kc++){
          ag[rf][cf] = MFMA(af[rf][kc], b1f[cf][kc], ag[rf][cf]);
          av[rf][cf] = MFMA(af[rf][kc], b2f[cf][kc], av[rf][cf]);
        }
  }
  // epilogue: act = gelu(G) * V, fp32 internal, one bf16 rounding
#pragma unroll
  for (int rf=0;rf<4;rf++){
#pragma unroll
    for (int cf=0;cf<4;cf++){
#pragma unroll
      for (int r=0;r<4;r++){
        int m = m0 + wm*64 + rf*16 + hi*4 + r;
        int n = n0 + wn*64 + cf*16 + lo;
        if (n < Nvalid){
          float g = ag[rf][cf][r];
          float v = av[rf][cf][r];
          float ga = 0.5f*g*(1.f + tanhf(0.7978845608028654f*(g + 0.044715f*g*g*g)));
          Cv[(size_t)m*ldc + n] = f2bf(ga * v);
        }
      }
    }
  }
}

// ---------------- RoPE ----------------
__global__ void rope_tab_kernel(float* __restrict__ tab){
  int s = blockIdx.x, i = threadIdx.x;             // s<1024, i<64
  float invf = __expf(-(float)i * (9.210340371976184f/64.f));  // 10000^(-i/64)
  float ph = (float)s * invf;
  float sn, cs;
  sincosf(ph, &sn, &cs);
  tab[s*128 + i] = cs;
  tab[s*128 + 64 + i] = sn;
}

__global__ __launch_bounds__(256) void rope_apply(ushort_t* __restrict__ qkv,
                                                  const float* __restrict__ tab){
  int idx = blockIdx.x*256 + threadIdx.x;          // 2048*40*64 total
  int pr = idx & 63;
  int h  = (idx >> 6) % 40;                        // 32 q heads + 8 k heads
  int row = idx / 2560;
  int t = row & (SEQ-1);
  ushort_t* p = qkv + (size_t)row*QKV_N + h*HD + pr;
  float c = tab[t*128 + pr], s = tab[t*128 + 64 + pr];
  float x1 = bf2f(p[0]), x2 = bf2f(p[64]);
  p[0]  = f2bf(x1*c - x2*s);
  p[64] = f2bf(x2*c + x1*s);
}

// ---------------- V transpose: VT[d][m] = qkv[m][5120+d] ----------------
__global__ __launch_bounds__(256) void transpose_v(const ushort_t* __restrict__ qkv,
                                                   ushort_t* __restrict__ VT){
  __shared__ ushort_t tile[32][33];
  int d0 = blockIdx.x*32, m0 = blockIdx.y*32;
  int tx = threadIdx.x & 31, ty = threadIdx.x >> 5;
#pragma unroll
  for (int i=0;i<4;i++)
    tile[ty + i*8][tx] = qkv[(size_t)(m0 + ty + i*8)*QKV_N + 5120 + d0 + tx];
  __syncthreads();
#pragma unroll
  for (int i=0;i<4;i++)
    VT[(size_t)(d0 + ty + i*8)*BROWS + m0 + tx] = tile[tx][ty + i*8];
}

// ---------------- Flash attention with tanh soft-cap, GQA, causal ----------------
__global__ __launch_bounds__(256) void attn_kernel(const ushort_t* __restrict__ qkv,
                                                   const ushort_t* __restrict__ VT,
                                                   ushort_t* __restrict__ outp){
  const int blk = blockIdx.x;
  const int bh = blk & 63;
  const int tgrp = 15 - (blk >> 6);     // heavy tiles dispatched first
  const int b = bh >> 5, qh = bh & 31, kv = qh >> 2;
  const int w = threadIdx.x >> 6, lane = threadIdx.x & 63;
  const int lo = lane & 15, hi = lane >> 4;
  const int t0 = tgrp*64 + w*16;
  __shared__ ushort_t P[4][16][72];     // per-wave P transpose buffer
  ushort_t (*Pw)[72] = P[w];

  const ushort_t* Qb = qkv + (size_t)(b*SEQ + t0 + lo)*QKV_N + qh*HD + hi*8;
  bf16x8 qf[4];
#pragma unroll
  for (int c=0;c<4;c++) qf[c] = ldb8(Qb + c*32);

  f32x4 of[8];
#pragma unroll
  for (int i=0;i<8;i++) of[i] = zero4();
  float ls[4] = {0.f,0.f,0.f,0.f};

  const ushort_t* Kb = qkv + (size_t)(b*SEQ + lo)*QKV_N + D_MODEL + kv*HD + hi*8;
  const ushort_t* Vb = VT + (size_t)(kv*HD + lo)*BROWS + b*SEQ + hi*8;

  const int nst = tgrp + 1;
  for (int st=0; st<nst; st++){
    const int s0 = st*64;
    f32x4 sacc[4];
#pragma unroll
    for (int nf=0;nf<4;nf++) sacc[nf] = zero4();
#pragma unroll
    for (int c=0;c<4;c++){
#pragma unroll
      for (int nf=0;nf<4;nf++){
        bf16x8 kf = ldb8(Kb + (size_t)(s0 + nf*16)*QKV_N + c*32);
        sacc[nf] = MFMA(qf[c], kf, sacc[nf]);
      }
    }
    // softmax (fixed max = 30 thanks to tanh cap) + write P^T to LDS
#pragma unroll
    for (int nf=0;nf<4;nf++){
#pragma unroll
      for (int r=0;r<4;r++){
        int tq = t0 + hi*4 + r;
        int s = s0 + nf*16 + lo;
        float xx = sacc[nf][r] * ATTN_MULT;
        float z = fminf(fmaxf(xx*(2.f/30.f), -80.f), 80.f);
        float e = __expf(z);
        float th = (e - 1.f)/(e + 1.f);
        float p = (s <= tq) ? __expf(30.f*th - 30.f) : 0.f;
        ls[r] += p;
        Pw[hi*4+r][nf*16+lo] = f2bf(p);
      }
    }
    __builtin_amdgcn_sched_barrier(0);
    __builtin_amdgcn_s_waitcnt(0xc07f);   // lgkmcnt(0): P writes visible wave-wide
    __builtin_amdgcn_sched_barrier(0);
#pragma unroll
    for (int c2=0;c2<2;c2++){
      bf16x8 pf = ldb8(&Pw[lo][c2*32 + hi*8]);
#pragma unroll
      for (int nf2=0;nf2<8;nf2++){
        bf16x8 vf = ldb8(Vb + (size_t)(nf2*16)*BROWS + s0 + c2*32);
        of[nf2] = MFMA(pf, vf, of[nf2]);
      }
    }
    __builtin_amdgcn_sched_barrier(0);
  }
#pragma unroll
  for (int m=1;m<16;m<<=1){
#pragma unroll
    for (int r=0;r<4;r++) ls[r] += __shfl_xor(ls[r], m);
  }
  float inv[4];
#pragma unroll
  for (int r=0;r<4;r++) inv[r] = 1.f/ls[r];
  ushort_t* Ob = outp + (size_t)(b*SEQ + t0 + hi*4)*D_MODEL + qh*HD + lo;
#pragma unroll
  for (int nf2=0;nf2<8;nf2++)
#pragma unroll
    for (int r=0;r<4;r++)
      Ob[(size_t)r*D_MODEL + nf2*16] = f2bf(of[nf2][r]*inv[r]);
}

// =============================== host launcher ===============================
extern "C" void kernel_launch(void* const* d_in, const int* in_sizes, int n_in,
                              void* d_out, int out_size, void* d_ws, size_t ws_size,
                              hipStream_t stream){
  const float* x        = (const float*)d_in[0];
  const float* sc_pre_a = (const float*)d_in[2];
  const float* sc_post_a= (const float*)d_in[3];
  const float* sc_pre_m = (const float*)d_in[4];
  const float* sc_post_m= (const float*)d_in[5];
  const float* wq  = (const float*)d_in[6];
  const float* wk  = (const float*)d_in[7];
  const float* wv  = (const float*)d_in[8];
  const float* wo  = (const float*)d_in[9];
  const float* wg  = (const float*)d_in[10];
  const float* wva = (const float*)d_in[11];
  const float* wou = (const float*)d_in[12];

  char* ws = (char*)d_ws;
  size_t off = 0;
  auto alloc = [&](size_t bytes)->void*{
    void* p = ws + off; off += (bytes + 255) & ~(size_t)255; return p;
  };
  ushort_t* WT   = (ushort_t*)alloc((size_t)FFN_GRID*D_MODEL*2); // reusable weight slot
  ushort_t* hn   = (ushort_t*)alloc((size_t)BROWS*D_MODEL*2);
  ushort_t* qkv  = (ushort_t*)alloc((size_t)BROWS*QKV_N*2);
  ushort_t* VT   = (ushort_t*)alloc((size_t)SEQ*BROWS*2);
  ushort_t* attn = (ushort_t*)alloc((size_t)BROWS*D_MODEL*2);
  float*    tmp32= (float*)alloc((size_t)BROWS*D_MODEL*4);
  ushort_t* hn2  = (ushort_t*)alloc((size_t)BROWS*D_MODEL*2);
  ushort_t* act  = (ushort_t*)alloc((size_t)BROWS*FFN_GRID*2);
  float*    rtab = (float*)alloc((size_t)SEQ*128*4);
  float* h = (float*)d_out;
  // WT2 (90.2 MB) overlays [hn .. tmp32] (96.5 MB) — all dead when gate/val runs.
  ushort_t* WT2  = (ushort_t*)hn;
  // split-K slice-1 partials reuse dead regions (no ws growth):
  float* part_o  = (float*)act;   // act free until gv writes it (after step 9)
  float* part_u  = (float*)hn;    // hn+qkv dead after attention; WT2 dead after gv

  // 1. pre-attn norm
  rmsnorm_in<<<BROWS, 256, 0, stream>>>(x, sc_pre_a, hn);
  // 2. convert wq|wk|wv -> WT[6144][4096]
  convT<<<dim3(64, 64), 256, 0, stream>>>(wq, WT,                     4096, 4096, 4096, 4096);
  convT<<<dim3(16, 64), 256, 0, stream>>>(wk, WT + (size_t)4096*4096, 4096, 1024, 4096, 1024);
  convT<<<dim3(16, 64), 256, 0, stream>>>(wv, WT + (size_t)5120*4096, 4096, 1024, 4096, 1024);
  // 3. fused QKV GEMM (BN=192: 8 m x 32 n = 256 blocks, 100% fill)
  gemmW<0,1,6><<<256, 512, 0, stream>>>(hn, 4096, WT, 4096, qkv, nullptr, QKV_N, QKV_N, 4096);
  // 4. RoPE on q,k
  rope_tab_kernel<<<SEQ, 64, 0, stream>>>(rtab);
  rope_apply<<<(BROWS*40*64)/256, 256, 0, stream>>>(qkv, rtab);
  // 5. V transpose for PV B-operand
  transpose_v<<<dim3(32,64), 256, 0, stream>>>(qkv, VT);
  // 6. attention
  attn_kernel<<<1024, 256, 0, stream>>>(qkv, VT, attn);
  // 7-8. O projection, split-K x2 (2 x 128 = 256 blocks, 100% fill)
  convT<<<dim3(64, 64), 256, 0, stream>>>(wo, WT, 4096, 4096, 4096, 4096);
  gemmW<1,2,8><<<256, 512, 0, stream>>>(attn, 4096, WT, 4096, tmp32, part_o, 4096, 4096, 2048);
  // 9. h = x + rms(o0+o1)*sc ; hn2 = rms(h)*sc_pre_mlp
  rmsnorm_resid<<<BROWS, 256, 0, stream>>>(x, tmp32, part_o, sc_post_a, h, sc_pre_m, hn2);
  // 10. convert wg -> WT, wva -> WT2
  convT<<<dim3(172, 64), 256, 0, stream>>>(wg,  WT,  4096, 10928, 4096, FFN_GRID);
  convT<<<dim3(172, 64), 256, 0, stream>>>(wva, WT2, 4096, 10928, 4096, FFN_GRID);
  // 11. fused gate+val GEMM (8 x 86 = 688 blocks): act = gelu(A@Wg^T) * (A@Wv^T)
  //     pad cols 10928..11008 written as exact zeros (WT pad rows are zero)
  gemm_gv<<<688, 512, 0, stream>>>(hn2, 4096, WT, WT2, 4096, act, FFN_GRID, FFN_GRID, 4096);
  // 12-13. out projection: K padded to 11008, split-K x2 (256 blocks, 100% fill)
  convT<<<dim3(64, 172), 256, 0, stream>>>(wou, WT, 10928, 4096, FFN_GRID, 4096);
  gemmW<1,2,8><<<256, 512, 0, stream>>>(act, FFN_GRID, WT, FFN_GRID, tmp32, part_u, 4096, 4096, 5504);
  // 14. final residual + norm (in-place on d_out)
  rmsnorm_resid<<<BROWS, 256, 0, stream>>>(h, tmp32, part_u, sc_post_m, h, nullptr, nullptr);
}